// Round 3
// baseline (263.209 us; speedup 1.0000x reference)
//
#include <hip/hip_runtime.h>
#include <hip/hip_bf16.h>

typedef __attribute__((ext_vector_type(8))) short bf16x8;
typedef __attribute__((ext_vector_type(4))) float f32x4;
typedef unsigned short u16;
typedef unsigned int u32;

#define MFMA16(a,b,c) __builtin_amdgcn_mfma_f32_16x16x32_bf16((a),(b),(c),0,0,0)

#define EXP2(x) exp2f(x)

// softmax scale folded into Q at projection time: (1/32) * log2(e)
#define QSCALE 0.045084220027780106f

__device__ __forceinline__ u16 f2bf(float f) {
  union { float f; unsigned int u; } v; v.f = f;
  unsigned int r = v.u + 0x7FFFu + ((v.u >> 16) & 1u);   // RNE
  return (u16)(r >> 16);
}

__device__ __forceinline__ u32 pkbf(float a, float b) {
  union { __hip_bfloat162 h; u32 u; } cv;
  cv.h = __float22bfloat162_rn(make_float2(a, b));
  return cv.u;
}

// async global->LDS, 16B per lane; LDS dest = uniform base + lane*16
__device__ __forceinline__ void gld16(const void* g, void* l) {
  __builtin_amdgcn_global_load_lds(
      (__attribute__((address_space(1))) void*)(g),
      (__attribute__((address_space(3))) void*)(l), 16, 0, 0);
}

// ---------------- cast fp32 -> bf16 (all inputs, one launch) ----------------
__global__ __launch_bounds__(256) void cast_all(
    const float* __restrict__ x, const float* __restrict__ qu,
    const float* __restrict__ wq, const float* __restrict__ wk,
    const float* __restrict__ wv, const float* __restrict__ wo,
    u16* __restrict__ xb, u16* __restrict__ qub,
    u16* __restrict__ wqb, u16* __restrict__ wkb,
    u16* __restrict__ wvb, u16* __restrict__ wob)
{
  int i = blockIdx.x * 256 + threadIdx.x;   // float4 index
  const float4* src; u16* dst; int off;
  if (i < 1048576)      { src = (const float4*)qu; dst = qub; off = i; }
  else if (i < 2097152) { src = (const float4*)x;  dst = xb;  off = i - 1048576; }
  else if (i < 2359296) { src = (const float4*)wq; dst = wqb; off = i - 2097152; }
  else if (i < 2621440) { src = (const float4*)wk; dst = wkb; off = i - 2359296; }
  else if (i < 2883584) { src = (const float4*)wv; dst = wvb; off = i - 2621440; }
  else                  { src = (const float4*)wo; dst = wob; off = i - 2883584; }
  float4 v = src[off];
  ushort4 r; r.x = f2bf(v.x); r.y = f2bf(v.y); r.z = f2bf(v.z); r.w = f2bf(v.w);
  ((ushort4*)dst)[off] = r;
}

// ---------------- fused QKV projection GEMM ----------------
// z=0: Q*(scale*log2e) -> [B,H,N,D]; z=1: K -> [B,H,N,D];
// z=2: V -> [B,H,D,N] transposed (identity token order) via LDS transpose.
__global__ __launch_bounds__(256) void gemm_qkv(
    const u16* __restrict__ qub, const u16* __restrict__ xb,
    const u16* __restrict__ wqb, const u16* __restrict__ wkb, const u16* __restrict__ wvb,
    const float* __restrict__ bq, const float* __restrict__ bk, const float* __restrict__ bv,
    u16* __restrict__ qhd, u16* __restrict__ khd, u16* __restrict__ vtd)
{
  __shared__ u16 sm2[2 * 128 * 64];   // As | Bs ; reused as transpose buf for z=2
  u16* As = sm2;
  u16* Bs = sm2 + 128 * 64;
  int tid = threadIdx.x, w = tid >> 6, lane = tid & 63;
  int c = lane & 15, quad = lane >> 4;
  int bm = blockIdx.x, bn = blockIdx.y, z = blockIdx.z;
  int wm = w >> 1, wn = w & 1;
  const u16* A = (z == 0) ? qub : xb;
  const u16* W = (z == 0) ? wqb : (z == 1) ? wkb : wvb;
  f32x4 acc[4][4] = {};
  for (int k0 = 0; k0 < 1024; k0 += 64) {
#pragma unroll
    for (int i = 0; i < 4; i++) {
      int seg = i * 256 + w * 64 + lane;          // physical 8-elem segment
      int row = seg >> 3, pseg = seg & 7;
      int lseg = pseg ^ (row & 7);                // logical k-segment (XOR swizzle)
      gld16(A + (size_t)(bm * 128 + row) * 1024 + k0 + lseg * 8,
            &As[(i * 256 + w * 64) * 8]);
      gld16(W + (size_t)(bn * 128 + row) * 1024 + k0 + lseg * 8,
            &Bs[(i * 256 + w * 64) * 8]);
    }
    __syncthreads();
#pragma unroll
    for (int ks = 0; ks < 2; ks++) {
      bf16x8 af[4], bfr[4];
#pragma unroll
      for (int mt = 0; mt < 4; mt++) {
        int row = wm * 64 + mt * 16 + c;
        int cseg = (ks * 4 + quad) ^ (row & 7);
        af[mt] = *(const bf16x8*)&As[(row * 8 + cseg) * 8];
      }
#pragma unroll
      for (int nt = 0; nt < 4; nt++) {
        int row = wn * 64 + nt * 16 + c;
        int cseg = (ks * 4 + quad) ^ (row & 7);
        bfr[nt] = *(const bf16x8*)&Bs[(row * 8 + cseg) * 8];
      }
#pragma unroll
      for (int mt = 0; mt < 4; mt++)
#pragma unroll
        for (int nt = 0; nt < 4; nt++)
          acc[mt][nt] = MFMA16(af[mt], bfr[nt], acc[mt][nt]);
    }
    __syncthreads();
  }
  if (z < 2) {
    const float* bias = (z == 0) ? bq : bk;
    u16* dst = (z == 0) ? qhd : khd;
#pragma unroll
    for (int nt = 0; nt < 4; nt++) {
      int o = bn * 128 + wn * 64 + nt * 16 + c;
      float bval = bias[o];
      int h = o >> 6, d = o & 63;
#pragma unroll
      for (int mt = 0; mt < 4; mt++)
#pragma unroll
        for (int j = 0; j < 4; j++) {
          int m = bm * 128 + wm * 64 + mt * 16 + quad * 4 + j;
          int b = m >> 11, n = m & 2047;
          float val = acc[mt][nt][j] + bval;
          if (z == 0)
            dst[((size_t)(b * 16 + h) * 2048 + n) * 64 + d] = f2bf(val * QSCALE);
          else
            dst[((size_t)(b * 16 + h) * 2048 + n) * 64 + d] = f2bf(val);
        }
    }
  } else {
    // V: transpose 128x128 C-tile -> [d][token] via LDS, two 64-row halves.
    u16* LT = sm2;   // [64][137] u16 = 17.1 KB
    for (int h2 = 0; h2 < 2; h2++) {
      if (wm == h2) {
#pragma unroll
        for (int nt = 0; nt < 4; nt++) {
          int o = bn * 128 + wn * 64 + nt * 16 + c;
          float bval = bv[o];
          int col = wn * 64 + nt * 16 + c;
#pragma unroll
          for (int mt = 0; mt < 4; mt++)
#pragma unroll
            for (int j = 0; j < 4; j++) {
              int rl = mt * 16 + quad * 4 + j;   // token-local 0..63
              LT[rl * 137 + col] = f2bf(acc[mt][nt][j] + bval);
            }
        }
      }
      __syncthreads();
      int m0 = bm * 128 + h2 * 64;
      int b = m0 >> 11, n0 = m0 & 2047;
      int tk0 = (tid & 7) * 8;
#pragma unroll
      for (int pass = 0; pass < 4; pass++) {
        int cl = pass * 32 + (tid >> 3);        // output channel local 0..127
        int o = bn * 128 + cl, hh = o >> 6, dd = o & 63;
        u16 tmp[8];
#pragma unroll
        for (int i = 0; i < 8; i++) tmp[i] = LT[(tk0 + i) * 137 + cl];
        uint4 pk4;
        pk4.x = ((u32)tmp[1] << 16) | tmp[0];
        pk4.y = ((u32)tmp[3] << 16) | tmp[2];
        pk4.z = ((u32)tmp[5] << 16) | tmp[4];
        pk4.w = ((u32)tmp[7] << 16) | tmp[6];
        *(uint4*)(vtd + ((size_t)(b * 16 + hh) * 64 + dd) * 2048 + n0 + tk0) = pk4;
      }
      __syncthreads();
    }
  }
}

// ---------------- attention v3: barrier-free self-contained waves ----------
// grid (32 qt, 32 bh), 4 waves. Wave w owns keys [w*512,(w+1)*512), all 64 q,
// all 64 d. S^T orientation: MFMA(Kfrag, Qfrag) -> S[key][q]; P round-trips a
// PRIVATE LDS band (no barriers in loop). Epilogue: cross-wave O reduction.
__global__ __launch_bounds__(256) void attn(
    const u16* __restrict__ qh, const u16* __restrict__ kh,
    const u16* __restrict__ vt, u16* __restrict__ ot)
{
  __shared__ __align__(16) char smraw[4 * 64 * 72 * 2];  // P bands / O-reduce union
  __shared__ float Ls[4][64];
  int tid = threadIdx.x, w = tid >> 6, lane = tid & 63;
  int c = lane & 15, quad = lane >> 4;
  int qt = blockIdx.x, bh = blockIdx.y;
  const u16* qp = qh + ((size_t)bh * 2048 + qt * 64) * 64;
  const u16* kp = kh + ((size_t)bh * 2048 + w * 512) * 64;
  const u16* vp = vt + (size_t)bh * 64 * 2048 + w * 512;
  u16* Pw = (u16*)smraw + w * (64 * 72);

  // Q B-frags in registers (invariant): B[k=d][n=q], lane c = q-col
  bf16x8 aq[4][2];
#pragma unroll
  for (int mt = 0; mt < 4; mt++)
#pragma unroll
    for (int ks = 0; ks < 2; ks++)
      aq[mt][ks] = *(const bf16x8*)(qp + (size_t)(mt * 16 + c) * 64 + ks * 32 + quad * 8);

  // K A-frags, ping-pong: A[m=key][k=d], lane c = key-row
  bf16x8 Ka[4][2], Kb[4][2];
#pragma unroll
  for (int nt = 0; nt < 4; nt++)
#pragma unroll
    for (int ks = 0; ks < 2; ks++)
      Ka[nt][ks] = *(const bf16x8*)(kp + (size_t)(nt * 16 + c) * 64 + ks * 32 + quad * 8);

  f32x4 O[4][4] = {};              // O[mt][dt]: q in mt*16.., d in dt*16..
  float ls[4] = {0.f, 0.f, 0.f, 0.f};

#define ATTN_STEP(IT, KC, KN)                                                   \
  {                                                                             \
    bf16x8 Vf[4][2];                                                            \
    _Pragma("unroll") for (int dt = 0; dt < 4; dt++)                            \
      _Pragma("unroll") for (int k2 = 0; k2 < 2; k2++)                          \
        Vf[dt][k2] = *(const bf16x8*)(vp + (size_t)(dt * 16 + c) * 2048 +       \
                                      (IT) * 64 + k2 * 32 + quad * 8);          \
    _Pragma("unroll") for (int mt = 0; mt < 4; mt++) {                          \
      f32x4 S0 = {}, S1 = {}, S2 = {}, S3 = {};                                 \
      S0 = MFMA16(KC[0][0], aq[mt][0], S0); S0 = MFMA16(KC[0][1], aq[mt][1], S0); \
      S1 = MFMA16(KC[1][0], aq[mt][0], S1); S1 = MFMA16(KC[1][1], aq[mt][1], S1); \
      S2 = MFMA16(KC[2][0], aq[mt][0], S2); S2 = MFMA16(KC[2][1], aq[mt][1], S2); \
      S3 = MFMA16(KC[3][0], aq[mt][0], S3); S3 = MFMA16(KC[3][1], aq[mt][1], S3); \
      u16* prow = &Pw[(mt * 16 + c) * 72 + quad * 4];                           \
      float p0, p1, p2, p3, sacc; uint2 pk;                                     \
      p0 = EXP2(S0[0]); p1 = EXP2(S0[1]); p2 = EXP2(S0[2]); p3 = EXP2(S0[3]);   \
      sacc = (p0 + p1) + (p2 + p3);                                             \
      pk.x = pkbf(p0, p1); pk.y = pkbf(p2, p3); *(uint2*)(prow) = pk;           \
      p0 = EXP2(S1[0]); p1 = EXP2(S1[1]); p2 = EXP2(S1[2]); p3 = EXP2(S1[3]);   \
      sacc += (p0 + p1) + (p2 + p3);                                            \
      pk.x = pkbf(p0, p1); pk.y = pkbf(p2, p3); *(uint2*)(prow + 16) = pk;      \
      p0 = EXP2(S2[0]); p1 = EXP2(S2[1]); p2 = EXP2(S2[2]); p3 = EXP2(S2[3]);   \
      sacc += (p0 + p1) + (p2 + p3);                                            \
      pk.x = pkbf(p0, p1); pk.y = pkbf(p2, p3); *(uint2*)(prow + 32) = pk;      \
      p0 = EXP2(S3[0]); p1 = EXP2(S3[1]); p2 = EXP2(S3[2]); p3 = EXP2(S3[3]);   \
      sacc += (p0 + p1) + (p2 + p3);                                            \
      pk.x = pkbf(p0, p1); pk.y = pkbf(p2, p3); *(uint2*)(prow + 48) = pk;      \
      ls[mt] += sacc;                                                           \
    }                                                                           \
    if ((IT) < 7) {                                                             \
      _Pragma("unroll") for (int nt = 0; nt < 4; nt++)                          \
        _Pragma("unroll") for (int ks = 0; ks < 2; ks++)                        \
          KN[nt][ks] = *(const bf16x8*)(kp +                                    \
              (size_t)(((IT) + 1) * 64 + nt * 16 + c) * 64 + ks * 32 + quad * 8); \
    }                                                                           \
    _Pragma("unroll") for (int mt = 0; mt < 4; mt++)                            \
      _Pragma("unroll") for (int k2 = 0; k2 < 2; k2++) {                        \
        bf16x8 pa = *(const bf16x8*)&Pw[(mt * 16 + c) * 72 + k2 * 32 + quad * 8]; \
        _Pragma("unroll") for (int dt = 0; dt < 4; dt++)                        \
          O[mt][dt] = MFMA16(pa, Vf[dt][k2], O[mt][dt]);                        \
      }                                                                         \
  }

  for (int ii = 0; ii < 4; ii++) {
    ATTN_STEP(2 * ii,     Ka, Kb)
    ATTN_STEP(2 * ii + 1, Kb, Ka)
  }
#undef ATTN_STEP

  // finalize per-wave row sums: reduce over quad (keys quarter-split)
#pragma unroll
  for (int mt = 0; mt < 4; mt++) {
    float s = ls[mt];
    s += __shfl_xor(s, 16);
    s += __shfl_xor(s, 32);
    ls[mt] = s;
  }
  __syncthreads();                      // all P-band reads done; reuse smraw
  if (lane < 16) {
#pragma unroll
    for (int mt = 0; mt < 4; mt++) Ls[w][mt * 16 + c] = ls[mt];
  }
  float* Ored = (float*)smraw;          // [4][32*68] fp32 = 34.8 KB
  float* Ow = Ored + w * (32 * 68);
  int b_ = bh >> 4, h = bh & 15;
  for (int r = 0; r < 2; r++) {
#pragma unroll
    for (int mh = 0; mh < 2; mh++) {
      int mt = r * 2 + mh;
#pragma unroll
      for (int dt = 0; dt < 4; dt++)
#pragma unroll
        for (int j = 0; j < 4; j++)
          Ow[(mh * 16 + quad * 4 + j) * 68 + dt * 16 + c] = O[mt][dt][j];
    }
    __syncthreads();
    {
      int qb = tid >> 3, d0 = (tid & 7) * 8;
      f32x4 sa = {}, sb = {};
#pragma unroll
      for (int ww = 0; ww < 4; ww++) {
        const float* src = Ored + ww * (32 * 68) + qb * 68 + d0;
        sa += *(const f32x4*)src;
        sb += *(const f32x4*)(src + 4);
      }
      int q64 = r * 32 + qb;
      float linv = 1.0f / (Ls[0][q64] + Ls[1][q64] + Ls[2][q64] + Ls[3][q64]);
      uint4 pk4;
      pk4.x = pkbf(sa[0] * linv, sa[1] * linv);
      pk4.y = pkbf(sa[2] * linv, sa[3] * linv);
      pk4.z = pkbf(sb[0] * linv, sb[1] * linv);
      pk4.w = pkbf(sb[2] * linv, sb[3] * linv);
      *(uint4*)(ot + (((size_t)b_ * 2048 + qt * 64 + q64) * 16 + h) * 64 + d0) = pk4;
    }
    __syncthreads();
  }
}

// ---------------- output projection GEMM (fp32 out), 64x128 tile ----------
__global__ __launch_bounds__(256) void gemm_out(
    const u16* __restrict__ Aot, const u16* __restrict__ wob,
    const float* __restrict__ bo, float* __restrict__ out)
{
  __shared__ u16 As[64 * 64];
  __shared__ u16 Bs[128 * 64];
  int tid = threadIdx.x, w = tid >> 6, lane = tid & 63;
  int bm = blockIdx.x, bn = blockIdx.y;
  int wm = w >> 1, wn = w & 1;
  f32x4 acc[2][4] = {};
  for (int k0 = 0; k0 < 1024; k0 += 64) {
#pragma unroll
    for (int i = 0; i < 2; i++) {
      int seg = i * 256 + tid;
      int row = seg >> 3, pseg = seg & 7;
      int lseg = pseg ^ (row & 7);
      gld16(Aot + (size_t)(bm * 64 + row) * 1024 + k0 + lseg * 8,
            &As[(i * 256 + tid - (tid & 7)) * 8 + (tid & 7) * 8]);
    }
#pragma unroll
    for (int i = 0; i < 4; i++) {
      int seg = i * 256 + tid;
      int row = seg >> 3, pseg = seg & 7;
      int lseg = pseg ^ (row & 7);
      gld16(wob + (size_t)(bn * 128 + row) * 1024 + k0 + lseg * 8,
            &Bs[(i * 256 + tid - (tid & 7)) * 8 + (tid & 7) * 8]);
    }
    __syncthreads();
#pragma unroll
    for (int ks = 0; ks < 2; ks++) {
      bf16x8 af[2], bfr[4];
#pragma unroll
      for (int mt = 0; mt < 2; mt++) {
        int row = wm * 32 + mt * 16 + (lane & 15);
        int cseg = (ks * 4 + (lane >> 4)) ^ (row & 7);
        af[mt] = *(const bf16x8*)&As[(row * 8 + cseg) * 8];
      }
#pragma unroll
      for (int nt = 0; nt < 4; nt++) {
        int row = wn * 64 + nt * 16 + (lane & 15);
        int cseg = (ks * 4 + (lane >> 4)) ^ (row & 7);
        bfr[nt] = *(const bf16x8*)&Bs[(row * 8 + cseg) * 8];
      }
#pragma unroll
      for (int mt = 0; mt < 2; mt++)
#pragma unroll
        for (int nt = 0; nt < 4; nt++)
          acc[mt][nt] = MFMA16(af[mt], bfr[nt], acc[mt][nt]);
    }
    __syncthreads();
  }
#pragma unroll
  for (int nt = 0; nt < 4; nt++) {
    int o = bn * 128 + wn * 64 + nt * 16 + (lane & 15);
    float bval = bo[o];
#pragma unroll
    for (int mt = 0; mt < 2; mt++)
#pragma unroll
      for (int j = 0; j < 4; j++) {
        int m = bm * 64 + wm * 32 + mt * 16 + (lane >> 4) * 4 + j;
        out[(size_t)m * 1024 + o] = acc[mt][nt][j] + bval;
      }
  }
}

extern "C" void kernel_launch(void* const* d_in, const int* in_sizes, int n_in,
                              void* d_out, int out_size, void* d_ws, size_t ws_size,
                              hipStream_t stream)
{
  const float* x  = (const float*)d_in[0];
  const float* qu = (const float*)d_in[1];
  const float* wq = (const float*)d_in[2];
  const float* bq = (const float*)d_in[3];
  const float* wk = (const float*)d_in[4];
  const float* bk = (const float*)d_in[5];
  const float* wv = (const float*)d_in[6];
  const float* bv = (const float*)d_in[7];
  const float* wo = (const float*)d_in[8];
  const float* bo = (const float*)d_in[9];
  float* out = (float*)d_out;
  char* ws = (char*)d_ws;
  u16* xb  = (u16*)(ws + (size_t)0);          // 8 MB
  u16* qub = (u16*)(ws + ((size_t)8  << 20)); // 8 MB
  u16* wqb = (u16*)(ws + ((size_t)16 << 20)); // 2 MB
  u16* wkb = (u16*)(ws + ((size_t)18 << 20)); // 2 MB
  u16* wvb = (u16*)(ws + ((size_t)20 << 20)); // 2 MB
  u16* wob = (u16*)(ws + ((size_t)22 << 20)); // 2 MB
  u16* qhd = (u16*)(ws + ((size_t)24 << 20)); // 8 MB  Q-scaled [B,H,N,D]
  u16* khd = (u16*)(ws + ((size_t)32 << 20)); // 8 MB  K [B,H,N,D]
  u16* vtd = (u16*)(ws + ((size_t)40 << 20)); // 8 MB  V^T [B,H,D,N]
  u16* otd = (u16*)(ws + ((size_t)48 << 20)); // 8 MB  attn out [B,N,H,D]

  cast_all<<<12288, 256, 0, stream>>>(x, qu, wq, wk, wv, wo,
                                      xb, qub, wqb, wkb, wvb, wob);
  gemm_qkv<<<dim3(32, 8, 3), 256, 0, stream>>>(qub, xb, wqb, wkb, wvb,
                                               bq, bk, bv, qhd, khd, vtd);
  attn<<<dim3(32, 32), 256, 0, stream>>>(qhd, khd, vtd, otd);
  gemm_out<<<dim3(64, 8), 256, 0, stream>>>(otd, wob, bo, out);
}

// Round 4
// 220.265 us; speedup vs baseline: 1.1950x; 1.1950x over previous
//
#include <hip/hip_runtime.h>
#include <hip/hip_bf16.h>

typedef __attribute__((ext_vector_type(8))) short bf16x8;
typedef __attribute__((ext_vector_type(4))) float f32x4;
typedef unsigned short u16;
typedef unsigned int u32;

#define MFMA16(a,b,c) __builtin_amdgcn_mfma_f32_16x16x32_bf16((a),(b),(c),0,0,0)

#if defined(__has_builtin) && __has_builtin(__builtin_amdgcn_exp2f)
#define EXP2(x) __builtin_amdgcn_exp2f(x)
#else
#define EXP2(x) exp2f(x)
#endif

// softmax scale folded into Q at projection time: (1/32) * log2(e)
#define QSCALE 0.045084220027780106f

__device__ __forceinline__ u16 f2bf(float f) {
  union { float f; unsigned int u; } v; v.f = f;
  unsigned int r = v.u + 0x7FFFu + ((v.u >> 16) & 1u);   // RNE
  return (u16)(r >> 16);
}

__device__ __forceinline__ u32 pkbf(float a, float b) {
  union { __hip_bfloat162 h; u32 u; } cv;
  cv.h = __float22bfloat162_rn(make_float2(a, b));
  return cv.u;
}

// async global->LDS, 16B per lane; LDS dest = wave-uniform base + lane*16
__device__ __forceinline__ void gld16(const void* g, void* l) {
  __builtin_amdgcn_global_load_lds(
      (__attribute__((address_space(1))) void*)(g),
      (__attribute__((address_space(3))) void*)(l), 16, 0, 0);
}

// ---------------- cast fp32 -> bf16 (all inputs, one launch) ----------------
__global__ __launch_bounds__(256) void cast_all(
    const float* __restrict__ x, const float* __restrict__ qu,
    const float* __restrict__ wq, const float* __restrict__ wk,
    const float* __restrict__ wv, const float* __restrict__ wo,
    u16* __restrict__ xb, u16* __restrict__ qub,
    u16* __restrict__ wqb, u16* __restrict__ wkb,
    u16* __restrict__ wvb, u16* __restrict__ wob)
{
  int i = blockIdx.x * 256 + threadIdx.x;   // float4 index
  const float4* src; u16* dst; int off;
  if (i < 1048576)      { src = (const float4*)qu; dst = qub; off = i; }
  else if (i < 2097152) { src = (const float4*)x;  dst = xb;  off = i - 1048576; }
  else if (i < 2359296) { src = (const float4*)wq; dst = wqb; off = i - 2097152; }
  else if (i < 2621440) { src = (const float4*)wk; dst = wkb; off = i - 2359296; }
  else if (i < 2883584) { src = (const float4*)wv; dst = wvb; off = i - 2621440; }
  else                  { src = (const float4*)wo; dst = wob; off = i - 2883584; }
  float4 v = src[off];
  ushort4 r; r.x = f2bf(v.x); r.y = f2bf(v.y); r.z = f2bf(v.z); r.w = f2bf(v.w);
  ((ushort4*)dst)[off] = r;
}

// ---------------- fused QKV projection GEMM ----------------
// z=0: Q*(scale*log2e) -> [B,H,N,D]; z=1: K -> [B,H,N,D];
// z=2: V -> [B,H,D,N'] transposed with per-64-tile token permutation
//      k' = (t&32) | ((t&12)<<1) | ((t&16)>>2) | (t&3), matching attn's
//      in-register P A-fragment key order.
__global__ __launch_bounds__(256) void gemm_qkv(
    const u16* __restrict__ qub, const u16* __restrict__ xb,
    const u16* __restrict__ wqb, const u16* __restrict__ wkb, const u16* __restrict__ wvb,
    const float* __restrict__ bq, const float* __restrict__ bk, const float* __restrict__ bv,
    u16* __restrict__ qhd, u16* __restrict__ khd, u16* __restrict__ vtd)
{
  __shared__ u16 sm2[2 * 128 * 64];   // As | Bs ; reused as transpose buf for z=2
  u16* As = sm2;
  u16* Bs = sm2 + 128 * 64;
  int tid = threadIdx.x, w = tid >> 6, lane = tid & 63;
  int c = lane & 15, quad = lane >> 4;
  int bm = blockIdx.x, bn = blockIdx.y, z = blockIdx.z;
  int wm = w >> 1, wn = w & 1;
  const u16* A = (z == 0) ? qub : xb;
  const u16* W = (z == 0) ? wqb : (z == 1) ? wkb : wvb;
  f32x4 acc[4][4] = {};
  for (int k0 = 0; k0 < 1024; k0 += 64) {
#pragma unroll
    for (int i = 0; i < 4; i++) {
      int seg = i * 256 + w * 64 + lane;          // physical 8-elem segment
      int row = seg >> 3, pseg = seg & 7;
      int lseg = pseg ^ (row & 7);                // logical k-segment (XOR swizzle)
      gld16(A + (size_t)(bm * 128 + row) * 1024 + k0 + lseg * 8,
            &As[(i * 256 + w * 64) * 8]);
      gld16(W + (size_t)(bn * 128 + row) * 1024 + k0 + lseg * 8,
            &Bs[(i * 256 + w * 64) * 8]);
    }
    __syncthreads();
#pragma unroll
    for (int ks = 0; ks < 2; ks++) {
      bf16x8 af[4], bfr[4];
#pragma unroll
      for (int mt = 0; mt < 4; mt++) {
        int row = wm * 64 + mt * 16 + c;
        int cseg = (ks * 4 + quad) ^ (row & 7);
        af[mt] = *(const bf16x8*)&As[(row * 8 + cseg) * 8];
      }
#pragma unroll
      for (int nt = 0; nt < 4; nt++) {
        int row = wn * 64 + nt * 16 + c;
        int cseg = (ks * 4 + quad) ^ (row & 7);
        bfr[nt] = *(const bf16x8*)&Bs[(row * 8 + cseg) * 8];
      }
#pragma unroll
      for (int mt = 0; mt < 4; mt++)
#pragma unroll
        for (int nt = 0; nt < 4; nt++)
          acc[mt][nt] = MFMA16(af[mt], bfr[nt], acc[mt][nt]);
    }
    __syncthreads();
  }
  if (z < 2) {
    const float* bias = (z == 0) ? bq : bk;
    u16* dst = (z == 0) ? qhd : khd;
#pragma unroll
    for (int nt = 0; nt < 4; nt++) {
      int o = bn * 128 + wn * 64 + nt * 16 + c;
      float bval = bias[o];
      int h = o >> 6, d = o & 63;
#pragma unroll
      for (int mt = 0; mt < 4; mt++)
#pragma unroll
        for (int j = 0; j < 4; j++) {
          int m = bm * 128 + wm * 64 + mt * 16 + quad * 4 + j;
          int b = m >> 11, n = m & 2047;
          float val = acc[mt][nt][j] + bval;
          if (z == 0)
            dst[((size_t)(b * 16 + h) * 2048 + n) * 64 + d] = f2bf(val * QSCALE);
          else
            dst[((size_t)(b * 16 + h) * 2048 + n) * 64 + d] = f2bf(val);
        }
    }
  } else {
    // V: transpose 128x128 C-tile -> [d][token'] via LDS, two 64-row halves,
    // applying the k' permutation on the token-local index.
    u16* LT = sm2;   // [64][137] u16 = 17.1 KB
    for (int h2 = 0; h2 < 2; h2++) {
      if (wm == h2) {
#pragma unroll
        for (int nt = 0; nt < 4; nt++) {
          int o = bn * 128 + wn * 64 + nt * 16 + c;
          float bval = bv[o];
          int col = wn * 64 + nt * 16 + c;
#pragma unroll
          for (int mt = 0; mt < 4; mt++)
#pragma unroll
            for (int j = 0; j < 4; j++) {
              int rl = mt * 16 + quad * 4 + j;   // token-local 0..63
              int krl = (rl & 32) | ((rl & 12) << 1) | ((rl & 16) >> 2) | (rl & 3);
              LT[krl * 137 + col] = f2bf(acc[mt][nt][j] + bval);
            }
        }
      }
      __syncthreads();
      int m0 = bm * 128 + h2 * 64;
      int b = m0 >> 11, n0 = m0 & 2047;
      int tk0 = (tid & 7) * 8;
#pragma unroll
      for (int pass = 0; pass < 4; pass++) {
        int cl = pass * 32 + (tid >> 3);        // output channel local 0..127
        int o = bn * 128 + cl, hh = o >> 6, dd = o & 63;
        u16 tmp[8];
#pragma unroll
        for (int i = 0; i < 8; i++) tmp[i] = LT[(tk0 + i) * 137 + cl];
        uint4 pk4;
        pk4.x = ((u32)tmp[1] << 16) | tmp[0];
        pk4.y = ((u32)tmp[3] << 16) | tmp[2];
        pk4.z = ((u32)tmp[5] << 16) | tmp[4];
        pk4.w = ((u32)tmp[7] << 16) | tmp[6];
        *(uint4*)(vtd + ((size_t)(b * 16 + hh) * 64 + dd) * 2048 + n0 + tk0) = pk4;
      }
      __syncthreads();
    }
  }
}

// ---------------- attention v4: S^T + in-register P, dbuf LDS K/V ----------
// grid (16 q-tiles of 128, 32 b*h) = 512 blocks = 2/CU. 4 waves; wave owns
// 32 q. S^T = MFMA(K,Q): lane c = q-col -> P is ALREADY the PV A-fragment
// after exp (V token-permuted at projection). One barrier per 64-key tile.
__global__ __launch_bounds__(256) void attn(
    const u16* __restrict__ qh, const u16* __restrict__ kh,
    const u16* __restrict__ vt, u16* __restrict__ ot)
{
  __shared__ u16 Kbuf[2][64 * 64];   // 16 KB, XOR-swizzled segments
  __shared__ u16 Vbuf[2][64 * 64];   // 16 KB
  __shared__ float Lw[4][32];
  int tid = threadIdx.x, w = tid >> 6, lane = tid & 63;
  int c = lane & 15, quad = lane >> 4;
  int qt = blockIdx.x, bh = blockIdx.y;
  const u16* qp = qh + ((size_t)bh * 2048 + qt * 128 + w * 32) * 64;
  const u16* kp = kh + (size_t)bh * 2048 * 64;
  const u16* vp = vt + (size_t)bh * 64 * 2048;

  // Q B-frags in registers: B[k=d][n=q], lane c = q-col
  bf16x8 Qf[2][2];
#pragma unroll
  for (int qt2 = 0; qt2 < 2; qt2++)
#pragma unroll
    for (int ks = 0; ks < 2; ks++)
      Qf[qt2][ks] = *(const bf16x8*)(qp + (size_t)(qt2 * 16 + c) * 64 + ks * 32 + quad * 8);

  // stage key-tile kt into buffer b (K: [key][d] rows, V: [d][tok'] rows)
#define STAGE(B, KT)                                                            \
  {                                                                             \
    _Pragma("unroll") for (int i = 0; i < 2; i++) {                             \
      int seg = i * 256 + tid;                                                  \
      int row = seg >> 3, ps = seg & 7, ls = ps ^ (row & 7);                    \
      gld16(kp + (size_t)((KT) * 64 + row) * 64 + ls * 8,                       \
            &Kbuf[B][(i * 256 + w * 64) * 8]);                                  \
      gld16(vp + (size_t)row * 2048 + (KT) * 64 + ls * 8,                       \
            &Vbuf[B][(i * 256 + w * 64) * 8]);                                  \
    }                                                                           \
  }

  STAGE(0, 0)
  __syncthreads();

  f32x4 O[2][4] = {};
  float ls0 = 0.f, ls1 = 0.f;
  for (int kt = 0; kt < 32; kt++) {
    int cur = kt & 1;
    if (kt < 31) STAGE(cur ^ 1, kt + 1)
    const u16* Ks = Kbuf[cur];
    const u16* Vs = Vbuf[cur];
    // K A-frags: A[m=key][k=d], lane c = key-row
    bf16x8 Kf[4][2];
#pragma unroll
    for (int nt = 0; nt < 4; nt++)
#pragma unroll
      for (int ks = 0; ks < 2; ks++) {
        int row = nt * 16 + c;
        Kf[nt][ks] = *(const bf16x8*)&Ks[(row * 8 + ((ks * 4 + quad) ^ (row & 7))) * 8];
      }
    // S^T: 16 MFMA
    f32x4 S[2][4] = {};
#pragma unroll
    for (int qt2 = 0; qt2 < 2; qt2++)
#pragma unroll
      for (int nt = 0; nt < 4; nt++) {
        S[qt2][nt] = MFMA16(Kf[nt][0], Qf[qt2][0], S[qt2][nt]);
        S[qt2][nt] = MFMA16(Kf[nt][1], Qf[qt2][1], S[qt2][nt]);
      }
    // exp -> packed PV A-frags (in-register, no LDS)
    bf16x8 pa[2][2];
#pragma unroll
    for (int qt2 = 0; qt2 < 2; qt2++)
#pragma unroll
      for (int i = 0; i < 2; i++) {
        float e0 = EXP2(S[qt2][2 * i][0]), e1 = EXP2(S[qt2][2 * i][1]);
        float e2 = EXP2(S[qt2][2 * i][2]), e3 = EXP2(S[qt2][2 * i][3]);
        float e4 = EXP2(S[qt2][2 * i + 1][0]), e5 = EXP2(S[qt2][2 * i + 1][1]);
        float e6 = EXP2(S[qt2][2 * i + 1][2]), e7 = EXP2(S[qt2][2 * i + 1][3]);
        float s = ((e0 + e1) + (e2 + e3)) + ((e4 + e5) + (e6 + e7));
        if (qt2 == 0) ls0 += s; else ls1 += s;
        union { uint4 u; bf16x8 v; } cv;
        cv.u.x = pkbf(e0, e1); cv.u.y = pkbf(e2, e3);
        cv.u.z = pkbf(e4, e5); cv.u.w = pkbf(e6, e7);
        pa[qt2][i] = cv.v;
      }
    // V B-frags: B[k'=tok'][n=d], lane c = d-col
    bf16x8 Vf[4][2];
#pragma unroll
    for (int dt = 0; dt < 4; dt++)
#pragma unroll
      for (int i = 0; i < 2; i++) {
        int row = dt * 16 + c;
        Vf[dt][i] = *(const bf16x8*)&Vs[(row * 8 + ((i * 4 + quad) ^ (row & 7))) * 8];
      }
    // PV: 16 MFMA
#pragma unroll
    for (int qt2 = 0; qt2 < 2; qt2++)
#pragma unroll
      for (int dt = 0; dt < 4; dt++) {
        O[qt2][dt] = MFMA16(pa[qt2][0], Vf[dt][0], O[qt2][dt]);
        O[qt2][dt] = MFMA16(pa[qt2][1], Vf[dt][1], O[qt2][dt]);
      }
    __syncthreads();   // guards buffer reuse; drains async stage
  }
#undef STAGE

  // row-sums: lane c holds partial for q=c; reduce over quads, publish
#pragma unroll
  for (int qt2 = 0; qt2 < 2; qt2++) {
    float s = (qt2 == 0) ? ls0 : ls1;
    s += __shfl_xor(s, 16);
    s += __shfl_xor(s, 32);
    if (lane < 16) Lw[w][qt2 * 16 + lane] = s;
  }
  // per-wave write->read; compiler inserts lgkmcnt wait
  int b_ = bh >> 4, h = bh & 15;
#pragma unroll
  for (int qt2 = 0; qt2 < 2; qt2++)
#pragma unroll
    for (int j = 0; j < 4; j++) {
      float linv = 1.0f / Lw[w][qt2 * 16 + quad * 4 + j];
      int n = qt * 128 + w * 32 + qt2 * 16 + quad * 4 + j;
      u16* op = ot + (((size_t)b_ * 2048 + n) * 16 + h) * 64;
#pragma unroll
      for (int dt = 0; dt < 4; dt++)
        op[dt * 16 + c] = f2bf(O[qt2][dt][j] * linv);
    }
}

// ---------------- output projection GEMM (fp32 out), 64x128 tile ----------
__global__ __launch_bounds__(256) void gemm_out(
    const u16* __restrict__ Aot, const u16* __restrict__ wob,
    const float* __restrict__ bo, float* __restrict__ out)
{
  __shared__ u16 As[64 * 64];
  __shared__ u16 Bs[128 * 64];
  int tid = threadIdx.x, w = tid >> 6, lane = tid & 63;
  int bm = blockIdx.x, bn = blockIdx.y;
  int wm = w >> 1, wn = w & 1;
  f32x4 acc[2][4] = {};
  for (int k0 = 0; k0 < 1024; k0 += 64) {
#pragma unroll
    for (int i = 0; i < 2; i++) {
      int seg = i * 256 + tid;
      int row = seg >> 3, pseg = seg & 7;
      int lseg = pseg ^ (row & 7);
      gld16(Aot + (size_t)(bm * 64 + row) * 1024 + k0 + lseg * 8,
            &As[(i * 256 + tid - (tid & 7)) * 8 + (tid & 7) * 8]);
    }
#pragma unroll
    for (int i = 0; i < 4; i++) {
      int seg = i * 256 + tid;
      int row = seg >> 3, pseg = seg & 7;
      int lseg = pseg ^ (row & 7);
      gld16(wob + (size_t)(bn * 128 + row) * 1024 + k0 + lseg * 8,
            &Bs[(i * 256 + tid - (tid & 7)) * 8 + (tid & 7) * 8]);
    }
    __syncthreads();
#pragma unroll
    for (int ks = 0; ks < 2; ks++) {
      bf16x8 af[2], bfr[4];
#pragma unroll
      for (int mt = 0; mt < 2; mt++) {
        int row = wm * 32 + mt * 16 + (lane & 15);
        int cseg = (ks * 4 + (lane >> 4)) ^ (row & 7);
        af[mt] = *(const bf16x8*)&As[(row * 8 + cseg) * 8];
      }
#pragma unroll
      for (int nt = 0; nt < 4; nt++) {
        int row = wn * 64 + nt * 16 + (lane & 15);
        int cseg = (ks * 4 + (lane >> 4)) ^ (row & 7);
        bfr[nt] = *(const bf16x8*)&Bs[(row * 8 + cseg) * 8];
      }
#pragma unroll
      for (int mt = 0; mt < 2; mt++)
#pragma unroll
        for (int nt = 0; nt < 4; nt++)
          acc[mt][nt] = MFMA16(af[mt], bfr[nt], acc[mt][nt]);
    }
    __syncthreads();
  }
#pragma unroll
  for (int nt = 0; nt < 4; nt++) {
    int o = bn * 128 + wn * 64 + nt * 16 + (lane & 15);
    float bval = bo[o];
#pragma unroll
    for (int mt = 0; mt < 2; mt++)
#pragma unroll
      for (int j = 0; j < 4; j++) {
        int m = bm * 64 + wm * 32 + mt * 16 + (lane >> 4) * 4 + j;
        out[(size_t)m * 1024 + o] = acc[mt][nt][j] + bval;
      }
  }
}

extern "C" void kernel_launch(void* const* d_in, const int* in_sizes, int n_in,
                              void* d_out, int out_size, void* d_ws, size_t ws_size,
                              hipStream_t stream)
{
  const float* x  = (const float*)d_in[0];
  const float* qu = (const float*)d_in[1];
  const float* wq = (const float*)d_in[2];
  const float* bq = (const float*)d_in[3];
  const float* wk = (const float*)d_in[4];
  const float* bk = (const float*)d_in[5];
  const float* wv = (const float*)d_in[6];
  const float* bv = (const float*)d_in[7];
  const float* wo = (const float*)d_in[8];
  const float* bo = (const float*)d_in[9];
  float* out = (float*)d_out;
  char* ws = (char*)d_ws;
  u16* xb  = (u16*)(ws + (size_t)0);          // 8 MB
  u16* qub = (u16*)(ws + ((size_t)8  << 20)); // 8 MB
  u16* wqb = (u16*)(ws + ((size_t)16 << 20)); // 2 MB
  u16* wkb = (u16*)(ws + ((size_t)18 << 20)); // 2 MB
  u16* wvb = (u16*)(ws + ((size_t)20 << 20)); // 2 MB
  u16* wob = (u16*)(ws + ((size_t)22 << 20)); // 2 MB
  u16* qhd = (u16*)(ws + ((size_t)24 << 20)); // 8 MB  Q-scaled [B,H,N,D]
  u16* khd = (u16*)(ws + ((size_t)32 << 20)); // 8 MB  K [B,H,N,D]
  u16* vtd = (u16*)(ws + ((size_t)40 << 20)); // 8 MB  V^T permuted [B,H,D,N']
  u16* otd = (u16*)(ws + ((size_t)48 << 20)); // 8 MB  attn out [B,N,H,D]

  cast_all<<<12288, 256, 0, stream>>>(x, qu, wq, wk, wv, wo,
                                      xb, qub, wqb, wkb, wvb, wob);
  gemm_qkv<<<dim3(32, 8, 3), 256, 0, stream>>>(qub, xb, wqb, wkb, wvb,
                                               bq, bk, bv, qhd, khd, vtd);
  attn<<<dim3(16, 32), 256, 0, stream>>>(qhd, khd, vtd, otd);
  gemm_out<<<dim3(64, 8), 256, 0, stream>>>(otd, wob, bo, out);
}

// Round 5
// 209.797 us; speedup vs baseline: 1.2546x; 1.0499x over previous
//
#include <hip/hip_runtime.h>
#include <hip/hip_bf16.h>

typedef __attribute__((ext_vector_type(8))) short bf16x8;
typedef __attribute__((ext_vector_type(4))) float f32x4;
typedef unsigned short u16;
typedef unsigned int u32;

#define MFMA16(a,b,c) __builtin_amdgcn_mfma_f32_16x16x32_bf16((a),(b),(c),0,0,0)

#if defined(__has_builtin) && __has_builtin(__builtin_amdgcn_exp2f)
#define EXP2(x) __builtin_amdgcn_exp2f(x)
#else
#define EXP2(x) exp2f(x)
#endif

// softmax scale folded into Q at projection time: (1/32) * log2(e)
#define QSCALE 0.045084220027780106f

__device__ __forceinline__ u16 f2bf(float f) {
  union { float f; unsigned int u; } v; v.f = f;
  unsigned int r = v.u + 0x7FFFu + ((v.u >> 16) & 1u);   // RNE
  return (u16)(r >> 16);
}

__device__ __forceinline__ u32 pkbf(float a, float b) {
  union { __hip_bfloat162 h; u32 u; } cv;
  cv.h = __float22bfloat162_rn(make_float2(a, b));
  return cv.u;
}

// async global->LDS, 16B per lane; LDS dest = wave-uniform base + lane*16
__device__ __forceinline__ void gld16(const void* g, void* l) {
  __builtin_amdgcn_global_load_lds(
      (__attribute__((address_space(1))) void*)(g),
      (__attribute__((address_space(3))) void*)(l), 16, 0, 0);
}

// ---------------- cast fp32 -> bf16 (all inputs, one launch) ----------------
__global__ __launch_bounds__(256) void cast_all(
    const float* __restrict__ x, const float* __restrict__ qu,
    const float* __restrict__ wq, const float* __restrict__ wk,
    const float* __restrict__ wv, const float* __restrict__ wo,
    u16* __restrict__ xb, u16* __restrict__ qub,
    u16* __restrict__ wqb, u16* __restrict__ wkb,
    u16* __restrict__ wvb, u16* __restrict__ wob)
{
  int i = blockIdx.x * 256 + threadIdx.x;   // float4 index
  const float4* src; u16* dst; int off;
  if (i < 1048576)      { src = (const float4*)qu; dst = qub; off = i; }
  else if (i < 2097152) { src = (const float4*)x;  dst = xb;  off = i - 1048576; }
  else if (i < 2359296) { src = (const float4*)wq; dst = wqb; off = i - 2097152; }
  else if (i < 2621440) { src = (const float4*)wk; dst = wkb; off = i - 2359296; }
  else if (i < 2883584) { src = (const float4*)wv; dst = wvb; off = i - 2621440; }
  else                  { src = (const float4*)wo; dst = wob; off = i - 2883584; }
  float4 v = src[off];
  ushort4 r; r.x = f2bf(v.x); r.y = f2bf(v.y); r.z = f2bf(v.z); r.w = f2bf(v.w);
  ((ushort4*)dst)[off] = r;
}

// ---------------- fused QKV projection GEMM ----------------
// z=0: Q*(scale*log2e) -> [B,H,N,D]; z=1: K -> [B,H,N,D];
// z=2: V -> [B,H,D,N'] transposed with per-64-tile token permutation
//      k' = (t&32) | ((t&12)<<1) | ((t&16)>>2) | (t&3), matching attn's
//      in-register P A-fragment key order.
__global__ __launch_bounds__(256) void gemm_qkv(
    const u16* __restrict__ qub, const u16* __restrict__ xb,
    const u16* __restrict__ wqb, const u16* __restrict__ wkb, const u16* __restrict__ wvb,
    const float* __restrict__ bq, const float* __restrict__ bk, const float* __restrict__ bv,
    u16* __restrict__ qhd, u16* __restrict__ khd, u16* __restrict__ vtd)
{
  __shared__ u16 sm2[2 * 128 * 64];   // As | Bs ; reused as transpose buf for z=2
  u16* As = sm2;
  u16* Bs = sm2 + 128 * 64;
  int tid = threadIdx.x, w = tid >> 6, lane = tid & 63;
  int c = lane & 15, quad = lane >> 4;
  int bm = blockIdx.x, bn = blockIdx.y, z = blockIdx.z;
  int wm = w >> 1, wn = w & 1;
  const u16* A = (z == 0) ? qub : xb;
  const u16* W = (z == 0) ? wqb : (z == 1) ? wkb : wvb;
  f32x4 acc[4][4] = {};
  for (int k0 = 0; k0 < 1024; k0 += 64) {
#pragma unroll
    for (int i = 0; i < 4; i++) {
      int seg = i * 256 + w * 64 + lane;          // physical 8-elem segment
      int row = seg >> 3, pseg = seg & 7;
      int lseg = pseg ^ (row & 7);                // logical k-segment (XOR swizzle)
      gld16(A + (size_t)(bm * 128 + row) * 1024 + k0 + lseg * 8,
            &As[(i * 256 + w * 64) * 8]);
      gld16(W + (size_t)(bn * 128 + row) * 1024 + k0 + lseg * 8,
            &Bs[(i * 256 + w * 64) * 8]);
    }
    __syncthreads();
#pragma unroll
    for (int ks = 0; ks < 2; ks++) {
      bf16x8 af[4], bfr[4];
#pragma unroll
      for (int mt = 0; mt < 4; mt++) {
        int row = wm * 64 + mt * 16 + c;
        int cseg = (ks * 4 + quad) ^ (row & 7);
        af[mt] = *(const bf16x8*)&As[(row * 8 + cseg) * 8];
      }
#pragma unroll
      for (int nt = 0; nt < 4; nt++) {
        int row = wn * 64 + nt * 16 + c;
        int cseg = (ks * 4 + quad) ^ (row & 7);
        bfr[nt] = *(const bf16x8*)&Bs[(row * 8 + cseg) * 8];
      }
#pragma unroll
      for (int mt = 0; mt < 4; mt++)
#pragma unroll
        for (int nt = 0; nt < 4; nt++)
          acc[mt][nt] = MFMA16(af[mt], bfr[nt], acc[mt][nt]);
    }
    __syncthreads();
  }
  if (z < 2) {
    const float* bias = (z == 0) ? bq : bk;
    u16* dst = (z == 0) ? qhd : khd;
#pragma unroll
    for (int nt = 0; nt < 4; nt++) {
      int o = bn * 128 + wn * 64 + nt * 16 + c;
      float bval = bias[o];
      int h = o >> 6, d = o & 63;
#pragma unroll
      for (int mt = 0; mt < 4; mt++)
#pragma unroll
        for (int j = 0; j < 4; j++) {
          int m = bm * 128 + wm * 64 + mt * 16 + quad * 4 + j;
          int b = m >> 11, n = m & 2047;
          float val = acc[mt][nt][j] + bval;
          if (z == 0)
            dst[((size_t)(b * 16 + h) * 2048 + n) * 64 + d] = f2bf(val * QSCALE);
          else
            dst[((size_t)(b * 16 + h) * 2048 + n) * 64 + d] = f2bf(val);
        }
    }
  } else {
    // V: transpose 128x128 C-tile -> [d][token'] via LDS, two 64-row halves,
    // applying the k' permutation on the token-local index.
    u16* LT = sm2;   // [64][137] u16 = 17.1 KB
    for (int h2 = 0; h2 < 2; h2++) {
      if (wm == h2) {
#pragma unroll
        for (int nt = 0; nt < 4; nt++) {
          int o = bn * 128 + wn * 64 + nt * 16 + c;
          float bval = bv[o];
          int col = wn * 64 + nt * 16 + c;
#pragma unroll
          for (int mt = 0; mt < 4; mt++)
#pragma unroll
            for (int j = 0; j < 4; j++) {
              int rl = mt * 16 + quad * 4 + j;   // token-local 0..63
              int krl = (rl & 32) | ((rl & 12) << 1) | ((rl & 16) >> 2) | (rl & 3);
              LT[krl * 137 + col] = f2bf(acc[mt][nt][j] + bval);
            }
        }
      }
      __syncthreads();
      int m0 = bm * 128 + h2 * 64;
      int b = m0 >> 11, n0 = m0 & 2047;
      int tk0 = (tid & 7) * 8;
#pragma unroll
      for (int pass = 0; pass < 4; pass++) {
        int cl = pass * 32 + (tid >> 3);        // output channel local 0..127
        int o = bn * 128 + cl, hh = o >> 6, dd = o & 63;
        u16 tmp[8];
#pragma unroll
        for (int i = 0; i < 8; i++) tmp[i] = LT[(tk0 + i) * 137 + cl];
        uint4 pk4;
        pk4.x = ((u32)tmp[1] << 16) | tmp[0];
        pk4.y = ((u32)tmp[3] << 16) | tmp[2];
        pk4.z = ((u32)tmp[5] << 16) | tmp[4];
        pk4.w = ((u32)tmp[7] << 16) | tmp[6];
        *(uint4*)(vtd + ((size_t)(b * 16 + hh) * 64 + dd) * 2048 + n0 + tk0) = pk4;
      }
      __syncthreads();
    }
  }
}

// ---------------- attention v5: v4 + VALU diet ----------------------------
// Same structure as v4 (S^T, in-register P, dbuf LDS K/V, 1 barrier/iter).
// Changes: (1) LDS frag addresses hoisted (row&7==c&7 -> 2 lane offsets +
// immediates; kt unrolled by 2 so buffer is compile-time), (2) staging
// pointers strength-reduced, (3) row-sums via MFMA(pa, ones) -> no VALU adds
// and no shuffle/LDS reduce epilogue.
__global__ __launch_bounds__(256) void attn(
    const u16* __restrict__ qh, const u16* __restrict__ kh,
    const u16* __restrict__ vt, u16* __restrict__ ot)
{
  __shared__ u16 Kbuf[2][64 * 64];   // 16 KB
  __shared__ u16 Vbuf[2][64 * 64];   // 16 KB
  int tid = threadIdx.x, w = tid >> 6, lane = tid & 63;
  int c = lane & 15, quad = lane >> 4;
  int qt = blockIdx.x, bh = blockIdx.y;
  const u16* qp = qh + ((size_t)bh * 2048 + qt * 128 + w * 32) * 64;

  // Q B-frags in registers: B[k=d][n=q], lane c = q-col
  bf16x8 Qf[2][2];
#pragma unroll
  for (int qt2 = 0; qt2 < 2; qt2++)
#pragma unroll
    for (int ks = 0; ks < 2; ks++)
      Qf[qt2][ks] = *(const bf16x8*)(qp + (size_t)(qt2 * 16 + c) * 64 + ks * 32 + quad * 8);

  // hoisted lane-invariant LDS fragment offsets (elements):
  // read addr = off{0,1} + tile*1024  (tile = nt or dt, immediate)
  int off0 = c * 64 + ((quad) ^ (c & 7)) * 8;
  int off1 = c * 64 + ((4 + quad) ^ (c & 7)) * 8;

  // strength-reduced staging pointers (advance by constants per tile)
  int srow = tid >> 3;                          // 0..31
  int sls  = (tid & 7) ^ (srow & 7);            // XOR swizzle
  const u16* kg0 = kh + (size_t)bh * 2048 * 64 + srow * 64 + sls * 8;
  const u16* kg1 = kg0 + 32 * 64;
  const u16* vg0 = vt + (size_t)bh * 64 * 2048 + srow * 2048 + sls * 8;
  const u16* vg1 = vg0 + 32 * 2048;
  // wave-uniform LDS dests per buffer
  u16* kd0[2] = {&Kbuf[0][(w * 64) * 8],       &Kbuf[1][(w * 64) * 8]};
  u16* kd1[2] = {&Kbuf[0][(256 + w * 64) * 8], &Kbuf[1][(256 + w * 64) * 8]};
  u16* vd0[2] = {&Vbuf[0][(w * 64) * 8],       &Vbuf[1][(w * 64) * 8]};
  u16* vd1[2] = {&Vbuf[0][(256 + w * 64) * 8], &Vbuf[1][(256 + w * 64) * 8]};

  // stage tile 0 into buffer 0
  gld16(kg0, kd0[0]); gld16(kg1, kd1[0]);
  gld16(vg0, vd0[0]); gld16(vg1, vd1[0]);
  kg0 += 4096; kg1 += 4096; vg0 += 64; vg1 += 64;
  __syncthreads();

  f32x4 O[2][4] = {};
  f32x4 Lacc[2] = {};
  bf16x8 vone;
#pragma unroll
  for (int j = 0; j < 8; j++) vone[j] = (short)0x3F80;   // bf16 1.0

#define ITER(PH, PREF)                                                          \
  {                                                                             \
    if (PREF) {                                                                 \
      gld16(kg0, kd0[PH ^ 1]); gld16(kg1, kd1[PH ^ 1]);                         \
      gld16(vg0, vd0[PH ^ 1]); gld16(vg1, vd1[PH ^ 1]);                         \
      kg0 += 4096; kg1 += 4096; vg0 += 64; vg1 += 64;                           \
    }                                                                           \
    const u16* Ks = Kbuf[PH];                                                   \
    const u16* Vs = Vbuf[PH];                                                   \
    bf16x8 Kf[4][2];                                                            \
    _Pragma("unroll") for (int nt = 0; nt < 4; nt++) {                          \
      Kf[nt][0] = *(const bf16x8*)&Ks[off0 + nt * 1024];                        \
      Kf[nt][1] = *(const bf16x8*)&Ks[off1 + nt * 1024];                        \
    }                                                                           \
    f32x4 S[2][4] = {};                                                         \
    _Pragma("unroll") for (int qt2 = 0; qt2 < 2; qt2++)                         \
      _Pragma("unroll") for (int nt = 0; nt < 4; nt++) {                        \
        S[qt2][nt] = MFMA16(Kf[nt][0], Qf[qt2][0], S[qt2][nt]);                 \
        S[qt2][nt] = MFMA16(Kf[nt][1], Qf[qt2][1], S[qt2][nt]);                 \
      }                                                                         \
    bf16x8 pa[2][2];                                                            \
    _Pragma("unroll") for (int qt2 = 0; qt2 < 2; qt2++)                         \
      _Pragma("unroll") for (int i = 0; i < 2; i++) {                           \
        float e0 = EXP2(S[qt2][2 * i][0]), e1 = EXP2(S[qt2][2 * i][1]);         \
        float e2 = EXP2(S[qt2][2 * i][2]), e3 = EXP2(S[qt2][2 * i][3]);         \
        float e4 = EXP2(S[qt2][2 * i + 1][0]), e5 = EXP2(S[qt2][2 * i + 1][1]); \
        float e6 = EXP2(S[qt2][2 * i + 1][2]), e7 = EXP2(S[qt2][2 * i + 1][3]); \
        union { uint4 u; bf16x8 v; } cv;                                        \
        cv.u.x = pkbf(e0, e1); cv.u.y = pkbf(e2, e3);                           \
        cv.u.z = pkbf(e4, e5); cv.u.w = pkbf(e6, e7);                           \
        pa[qt2][i] = cv.v;                                                      \
      }                                                                         \
    Lacc[0] = MFMA16(pa[0][0], vone, Lacc[0]);                                  \
    Lacc[0] = MFMA16(pa[0][1], vone, Lacc[0]);                                  \
    Lacc[1] = MFMA16(pa[1][0], vone, Lacc[1]);                                  \
    Lacc[1] = MFMA16(pa[1][1], vone, Lacc[1]);                                  \
    bf16x8 Vf[4][2];                                                            \
    _Pragma("unroll") for (int dt = 0; dt < 4; dt++) {                          \
      Vf[dt][0] = *(const bf16x8*)&Vs[off0 + dt * 1024];                        \
      Vf[dt][1] = *(const bf16x8*)&Vs[off1 + dt * 1024];                        \
    }                                                                           \
    _Pragma("unroll") for (int qt2 = 0; qt2 < 2; qt2++)                         \
      _Pragma("unroll") for (int dt = 0; dt < 4; dt++) {                        \
        O[qt2][dt] = MFMA16(pa[qt2][0], Vf[dt][0], O[qt2][dt]);                 \
        O[qt2][dt] = MFMA16(pa[qt2][1], Vf[dt][1], O[qt2][dt]);                 \
      }                                                                         \
    __syncthreads();                                                            \
  }

  for (int kt2 = 0; kt2 < 15; kt2++) {
    ITER(0, 1)
    ITER(1, 1)
  }
  ITER(0, 1)
  ITER(1, 0)
#undef ITER

  // epilogue: Lacc[qt2][j] = row-sum for q = qt2*16 + quad*4 + j (all c equal)
  int b_ = bh >> 4, h = bh & 15;
#pragma unroll
  for (int qt2 = 0; qt2 < 2; qt2++) {
    f32x4 linv;
#pragma unroll
    for (int j = 0; j < 4; j++) linv[j] = 1.0f / Lacc[qt2][j];
#pragma unroll
    for (int j = 0; j < 4; j++) {
      int n = qt * 128 + w * 32 + qt2 * 16 + quad * 4 + j;
      u16* op = ot + (((size_t)b_ * 2048 + n) * 16 + h) * 64;
#pragma unroll
      for (int dt = 0; dt < 4; dt++)
        op[dt * 16 + c] = f2bf(O[qt2][dt][j] * linv[j]);
    }
  }
}

// ---------------- output projection GEMM (fp32 out), 64x128 tile ----------
__global__ __launch_bounds__(256) void gemm_out(
    const u16* __restrict__ Aot, const u16* __restrict__ wob,
    const float* __restrict__ bo, float* __restrict__ out)
{
  __shared__ u16 As[64 * 64];
  __shared__ u16 Bs[128 * 64];
  int tid = threadIdx.x, w = tid >> 6, lane = tid & 63;
  int bm = blockIdx.x, bn = blockIdx.y;
  int wm = w >> 1, wn = w & 1;
  f32x4 acc[2][4] = {};
  for (int k0 = 0; k0 < 1024; k0 += 64) {
#pragma unroll
    for (int i = 0; i < 2; i++) {
      int seg = i * 256 + tid;
      int row = seg >> 3, pseg = seg & 7;
      int lseg = pseg ^ (row & 7);
      gld16(Aot + (size_t)(bm * 64 + row) * 1024 + k0 + lseg * 8,
            &As[(i * 256 + tid - (tid & 7)) * 8 + (tid & 7) * 8]);
    }
#pragma unroll
    for (int i = 0; i < 4; i++) {
      int seg = i * 256 + tid;
      int row = seg >> 3, pseg = seg & 7;
      int lseg = pseg ^ (row & 7);
      gld16(wob + (size_t)(bn * 128 + row) * 1024 + k0 + lseg * 8,
            &Bs[(i * 256 + tid - (tid & 7)) * 8 + (tid & 7) * 8]);
    }
    __syncthreads();
#pragma unroll
    for (int ks = 0; ks < 2; ks++) {
      bf16x8 af[2], bfr[4];
#pragma unroll
      for (int mt = 0; mt < 2; mt++) {
        int row = wm * 32 + mt * 16 + (lane & 15);
        int cseg = (ks * 4 + (lane >> 4)) ^ (row & 7);
        af[mt] = *(const bf16x8*)&As[(row * 8 + cseg) * 8];
      }
#pragma unroll
      for (int nt = 0; nt < 4; nt++) {
        int row = wn * 64 + nt * 16 + (lane & 15);
        int cseg = (ks * 4 + (lane >> 4)) ^ (row & 7);
        bfr[nt] = *(const bf16x8*)&Bs[(row * 8 + cseg) * 8];
      }
#pragma unroll
      for (int mt = 0; mt < 2; mt++)
#pragma unroll
        for (int nt = 0; nt < 4; nt++)
          acc[mt][nt] = MFMA16(af[mt], bfr[nt], acc[mt][nt]);
    }
    __syncthreads();
  }
#pragma unroll
  for (int nt = 0; nt < 4; nt++) {
    int o = bn * 128 + wn * 64 + nt * 16 + (lane & 15);
    float bval = bo[o];
#pragma unroll
    for (int mt = 0; mt < 2; mt++)
#pragma unroll
      for (int j = 0; j < 4; j++) {
        int m = bm * 64 + wm * 32 + mt * 16 + (lane >> 4) * 4 + j;
        out[(size_t)m * 1024 + o] = acc[mt][nt][j] + bval;
      }
  }
}

extern "C" void kernel_launch(void* const* d_in, const int* in_sizes, int n_in,
                              void* d_out, int out_size, void* d_ws, size_t ws_size,
                              hipStream_t stream)
{
  const float* x  = (const float*)d_in[0];
  const float* qu = (const float*)d_in[1];
  const float* wq = (const float*)d_in[2];
  const float* bq = (const float*)d_in[3];
  const float* wk = (const float*)d_in[4];
  const float* bk = (const float*)d_in[5];
  const float* wv = (const float*)d_in[6];
  const float* bv = (const float*)d_in[7];
  const float* wo = (const float*)d_in[8];
  const float* bo = (const float*)d_in[9];
  float* out = (float*)d_out;
  char* ws = (char*)d_ws;
  u16* xb  = (u16*)(ws + (size_t)0);          // 8 MB
  u16* qub = (u16*)(ws + ((size_t)8  << 20)); // 8 MB
  u16* wqb = (u16*)(ws + ((size_t)16 << 20)); // 2 MB
  u16* wkb = (u16*)(ws + ((size_t)18 << 20)); // 2 MB
  u16* wvb = (u16*)(ws + ((size_t)20 << 20)); // 2 MB
  u16* wob = (u16*)(ws + ((size_t)22 << 20)); // 2 MB
  u16* qhd = (u16*)(ws + ((size_t)24 << 20)); // 8 MB  Q-scaled [B,H,N,D]
  u16* khd = (u16*)(ws + ((size_t)32 << 20)); // 8 MB  K [B,H,N,D]
  u16* vtd = (u16*)(ws + ((size_t)40 << 20)); // 8 MB  V^T permuted [B,H,D,N']
  u16* otd = (u16*)(ws + ((size_t)48 << 20)); // 8 MB  attn out [B,N,H,D]

  cast_all<<<12288, 256, 0, stream>>>(x, qu, wq, wk, wv, wo,
                                      xb, qub, wqb, wkb, wvb, wob);
  gemm_qkv<<<dim3(32, 8, 3), 256, 0, stream>>>(qub, xb, wqb, wkb, wvb,
                                               bq, bk, bv, qhd, khd, vtd);
  attn<<<dim3(16, 32), 256, 0, stream>>>(qhd, khd, vtd, otd);
  gemm_out<<<dim3(64, 8), 256, 0, stream>>>(otd, wob, bo, out);
}

// Round 6
// 204.207 us; speedup vs baseline: 1.2889x; 1.0274x over previous
//
#include <hip/hip_runtime.h>
#include <hip/hip_bf16.h>

typedef __attribute__((ext_vector_type(8))) short bf16x8;
typedef __attribute__((ext_vector_type(4))) float f32x4;
typedef unsigned short u16;
typedef unsigned int u32;

#define MFMA16(a,b,c) __builtin_amdgcn_mfma_f32_16x16x32_bf16((a),(b),(c),0,0,0)

#if defined(__has_builtin) && __has_builtin(__builtin_amdgcn_exp2f)
#define EXP2(x) __builtin_amdgcn_exp2f(x)
#else
#define EXP2(x) exp2f(x)
#endif

// softmax scale folded into Q at projection time: (1/32) * log2(e)
#define QSCALE 0.045084220027780106f

__device__ __forceinline__ u16 f2bf(float f) {
  union { float f; unsigned int u; } v; v.f = f;
  unsigned int r = v.u + 0x7FFFu + ((v.u >> 16) & 1u);   // RNE
  return (u16)(r >> 16);
}

__device__ __forceinline__ u32 pkbf(float a, float b) {
  union { __hip_bfloat162 h; u32 u; } cv;
  cv.h = __float22bfloat162_rn(make_float2(a, b));
  return cv.u;
}

// async global->LDS, 16B per lane; LDS dest = wave-uniform base + lane*16
__device__ __forceinline__ void gld16(const void* g, void* l) {
  __builtin_amdgcn_global_load_lds(
      (__attribute__((address_space(1))) void*)(g),
      (__attribute__((address_space(3))) void*)(l), 16, 0, 0);
}

// ---------------- cast fp32 -> bf16 (all inputs, one launch) ----------------
__global__ __launch_bounds__(256) void cast_all(
    const float* __restrict__ x, const float* __restrict__ qu,
    const float* __restrict__ wq, const float* __restrict__ wk,
    const float* __restrict__ wv, const float* __restrict__ wo,
    u16* __restrict__ xb, u16* __restrict__ qub,
    u16* __restrict__ wqb, u16* __restrict__ wkb,
    u16* __restrict__ wvb, u16* __restrict__ wob)
{
  int i = blockIdx.x * 256 + threadIdx.x;   // float4 index
  const float4* src; u16* dst; int off;
  if (i < 1048576)      { src = (const float4*)qu; dst = qub; off = i; }
  else if (i < 2097152) { src = (const float4*)x;  dst = xb;  off = i - 1048576; }
  else if (i < 2359296) { src = (const float4*)wq; dst = wqb; off = i - 2097152; }
  else if (i < 2621440) { src = (const float4*)wk; dst = wkb; off = i - 2359296; }
  else if (i < 2883584) { src = (const float4*)wv; dst = wvb; off = i - 2621440; }
  else                  { src = (const float4*)wo; dst = wob; off = i - 2883584; }
  float4 v = src[off];
  ushort4 r; r.x = f2bf(v.x); r.y = f2bf(v.y); r.z = f2bf(v.z); r.w = f2bf(v.w);
  ((ushort4*)dst)[off] = r;
}

// ---------------- fused QKV projection GEMM ----------------
// z=0: Q*(scale*log2e) -> [B,H,N,D]; z=1: K -> [B,H,N,D]  — computed as C^T
//      (swap MFMA operands) so each lane holds 4 consecutive channels ->
//      packed 8-B stores, no LDS transpose.
// z=2: V -> [B,H,D,N'] — normal orientation: lane j-values are 4 consecutive
//      permuted tokens (k' = (mt&2)*16 + quad*8 + (mt&1)*4 + j) -> packed
//      8-B stores directly into the transposed layout.
__global__ __launch_bounds__(256) void gemm_qkv(
    const u16* __restrict__ qub, const u16* __restrict__ xb,
    const u16* __restrict__ wqb, const u16* __restrict__ wkb, const u16* __restrict__ wvb,
    const float* __restrict__ bq, const float* __restrict__ bk, const float* __restrict__ bv,
    u16* __restrict__ qhd, u16* __restrict__ khd, u16* __restrict__ vtd)
{
  __shared__ u16 As[128 * 64];
  __shared__ u16 Bs[128 * 64];
  int tid = threadIdx.x, w = tid >> 6, lane = tid & 63;
  int c = lane & 15, quad = lane >> 4;
  int bm = blockIdx.x, bn = blockIdx.y, z = blockIdx.z;
  int wm = w >> 1, wn = w & 1;
  const u16* A = (z == 0) ? qub : xb;
  const u16* W = (z == 0) ? wqb : (z == 1) ? wkb : wvb;
  f32x4 acc[4][4] = {};
  for (int k0 = 0; k0 < 1024; k0 += 64) {
#pragma unroll
    for (int i = 0; i < 4; i++) {
      int seg = i * 256 + w * 64 + lane;          // physical 8-elem segment
      int row = seg >> 3, pseg = seg & 7;
      int lseg = pseg ^ (row & 7);                // logical k-segment (XOR swizzle)
      gld16(A + (size_t)(bm * 128 + row) * 1024 + k0 + lseg * 8,
            &As[(i * 256 + w * 64) * 8]);
      gld16(W + (size_t)(bn * 128 + row) * 1024 + k0 + lseg * 8,
            &Bs[(i * 256 + w * 64) * 8]);
    }
    __syncthreads();
#pragma unroll
    for (int ks = 0; ks < 2; ks++) {
      bf16x8 af[4], bfr[4];
#pragma unroll
      for (int mt = 0; mt < 4; mt++) {
        int row = wm * 64 + mt * 16 + c;
        int cseg = (ks * 4 + quad) ^ (row & 7);
        af[mt] = *(const bf16x8*)&As[(row * 8 + cseg) * 8];
      }
#pragma unroll
      for (int nt = 0; nt < 4; nt++) {
        int row = wn * 64 + nt * 16 + c;
        int cseg = (ks * 4 + quad) ^ (row & 7);
        bfr[nt] = *(const bf16x8*)&Bs[(row * 8 + cseg) * 8];
      }
      if (z < 2) {
        // C^T: rows = channels (W frags as A-operand), cols = tokens
#pragma unroll
        for (int ct = 0; ct < 4; ct++)
#pragma unroll
          for (int tt = 0; tt < 4; tt++)
            acc[ct][tt] = MFMA16(bfr[ct], af[tt], acc[ct][tt]);
      } else {
#pragma unroll
        for (int mt = 0; mt < 4; mt++)
#pragma unroll
          for (int nt = 0; nt < 4; nt++)
            acc[mt][nt] = MFMA16(af[mt], bfr[nt], acc[mt][nt]);
      }
    }
    __syncthreads();
  }
  if (z < 2) {
    const float* bias = (z == 0) ? bq : bk;
    u16* dst = (z == 0) ? qhd : khd;
    float sc = (z == 0) ? QSCALE : 1.0f;
    // per-lane bias for 4 consecutive channels per ct (16B-aligned)
    float4 bbs[4];
#pragma unroll
    for (int ct = 0; ct < 4; ct++) {
      float4 b4 = *(const float4*)&bias[bn * 128 + wn * 64 + ct * 16 + quad * 4];
      bbs[ct].x = b4.x * sc; bbs[ct].y = b4.y * sc;
      bbs[ct].z = b4.z * sc; bbs[ct].w = b4.w * sc;
    }
#pragma unroll
    for (int ct = 0; ct < 4; ct++) {
      int ch = bn * 128 + wn * 64 + ct * 16 + quad * 4;
      int h = ch >> 6, d0 = ch & 63;
#pragma unroll
      for (int tt = 0; tt < 4; tt++) {
        int tok = bm * 128 + wm * 64 + tt * 16 + c;
        int b = tok >> 11, n = tok & 2047;
        float v0 = fmaf(acc[ct][tt][0], sc, bbs[ct].x);
        float v1 = fmaf(acc[ct][tt][1], sc, bbs[ct].y);
        float v2 = fmaf(acc[ct][tt][2], sc, bbs[ct].z);
        float v3 = fmaf(acc[ct][tt][3], sc, bbs[ct].w);
        uint2 pk; pk.x = pkbf(v0, v1); pk.y = pkbf(v2, v3);
        *(uint2*)&dst[((size_t)(b * 16 + h) * 2048 + n) * 64 + d0] = pk;
      }
    }
  } else {
    float bval[4];
#pragma unroll
    for (int nt = 0; nt < 4; nt++)
      bval[nt] = bv[bn * 128 + wn * 64 + nt * 16 + c];
#pragma unroll
    for (int mt = 0; mt < 4; mt++) {
      int tokl = (mt & 2) * 16 + quad * 8 + (mt & 1) * 4;   // permuted, +j
      int tok = bm * 128 + wm * 64 + tokl;
      int b = tok >> 11, np = tok & 2047;
#pragma unroll
      for (int nt = 0; nt < 4; nt++) {
        int ch = bn * 128 + wn * 64 + nt * 16 + c;
        int h = ch >> 6, d = ch & 63;
        float v0 = acc[mt][nt][0] + bval[nt];
        float v1 = acc[mt][nt][1] + bval[nt];
        float v2 = acc[mt][nt][2] + bval[nt];
        float v3 = acc[mt][nt][3] + bval[nt];
        uint2 pk; pk.x = pkbf(v0, v1); pk.y = pkbf(v2, v3);
        *(uint2*)&vtd[((size_t)(b * 16 + h) * 64 + d) * 2048 + np] = pk;
      }
    }
  }
}

// ---------------- attention v6: v5 per-wave code, 4 blocks/CU -------------
// grid (32 bh, 32 qt): 1024 blocks of 128 threads (2 waves), 64-q tile,
// wave owns 32 q. Same-bh blocks land on one XCD (linear%8 heuristic).
// S^T + in-register P + dbuf LDS K/V, 1 barrier/iter.
__global__ __launch_bounds__(128) void attn(
    const u16* __restrict__ qh, const u16* __restrict__ kh,
    const u16* __restrict__ vt, u16* __restrict__ ot)
{
  __shared__ u16 Kbuf[2][64 * 64];   // 8 KB each buf
  __shared__ u16 Vbuf[2][64 * 64];
  int tid = threadIdx.x, w = tid >> 6, lane = tid & 63;
  int c = lane & 15, quad = lane >> 4;
  int bh = blockIdx.x, qt = blockIdx.y;
  const u16* qp = qh + ((size_t)bh * 2048 + qt * 64 + w * 32) * 64;

  // Q B-frags in registers: B[k=d][n=q], lane c = q-col
  bf16x8 Qf[2][2];
#pragma unroll
  for (int qt2 = 0; qt2 < 2; qt2++)
#pragma unroll
    for (int ks = 0; ks < 2; ks++)
      Qf[qt2][ks] = *(const bf16x8*)(qp + (size_t)(qt2 * 16 + c) * 64 + ks * 32 + quad * 8);

  // hoisted lane-invariant LDS fragment offsets (elements)
  int off0 = c * 64 + ((quad) ^ (c & 7)) * 8;
  int off1 = c * 64 + ((4 + quad) ^ (c & 7)) * 8;

  // staging: wave w covers rows {c2*16 + w*8 + (lane>>3)}, c2 = 0..3
  int sr = lane >> 3;                 // 0..7
  int row0 = w * 8 + sr;              // 0..15 ; row0&7 == sr&7
  int sls = (lane & 7) ^ (sr & 7);    // XOR swizzle
  const u16* kg = kh + (size_t)bh * 2048 * 64 + row0 * 64 + sls * 8;
  const u16* vg = vt + (size_t)bh * 64 * 2048 + row0 * 2048 + sls * 8;

#define STAGE(B)                                                                \
  {                                                                             \
    gld16(kg,          &Kbuf[B][(w * 64) * 8]);                                 \
    gld16(kg + 1024,   &Kbuf[B][(128 + w * 64) * 8]);                           \
    gld16(kg + 2048,   &Kbuf[B][(256 + w * 64) * 8]);                           \
    gld16(kg + 3072,   &Kbuf[B][(384 + w * 64) * 8]);                           \
    gld16(vg,          &Vbuf[B][(w * 64) * 8]);                                 \
    gld16(vg + 32768,  &Vbuf[B][(128 + w * 64) * 8]);                           \
    gld16(vg + 65536,  &Vbuf[B][(256 + w * 64) * 8]);                           \
    gld16(vg + 98304,  &Vbuf[B][(384 + w * 64) * 8]);                           \
    kg += 4096; vg += 64;                                                       \
  }

  STAGE(0)
  __syncthreads();

  f32x4 O[2][4] = {};
  f32x4 Lacc[2] = {};
  bf16x8 vone;
#pragma unroll
  for (int j = 0; j < 8; j++) vone[j] = (short)0x3F80;   // bf16 1.0

#define ITER(PH, PREF)                                                          \
  {                                                                             \
    if (PREF) STAGE(PH ^ 1)                                                     \
    const u16* Ks = Kbuf[PH];                                                   \
    const u16* Vs = Vbuf[PH];                                                   \
    bf16x8 Kf[4][2];                                                            \
    _Pragma("unroll") for (int nt = 0; nt < 4; nt++) {                          \
      Kf[nt][0] = *(const bf16x8*)&Ks[off0 + nt * 1024];                        \
      Kf[nt][1] = *(const bf16x8*)&Ks[off1 + nt * 1024];                        \
    }                                                                           \
    f32x4 S[2][4] = {};                                                         \
    _Pragma("unroll") for (int qt2 = 0; qt2 < 2; qt2++)                         \
      _Pragma("unroll") for (int nt = 0; nt < 4; nt++) {                        \
        S[qt2][nt] = MFMA16(Kf[nt][0], Qf[qt2][0], S[qt2][nt]);                 \
        S[qt2][nt] = MFMA16(Kf[nt][1], Qf[qt2][1], S[qt2][nt]);                 \
      }                                                                         \
    bf16x8 pa[2][2];                                                            \
    _Pragma("unroll") for (int qt2 = 0; qt2 < 2; qt2++)                         \
      _Pragma("unroll") for (int i = 0; i < 2; i++) {                           \
        float e0 = EXP2(S[qt2][2 * i][0]), e1 = EXP2(S[qt2][2 * i][1]);         \
        float e2 = EXP2(S[qt2][2 * i][2]), e3 = EXP2(S[qt2][2 * i][3]);         \
        float e4 = EXP2(S[qt2][2 * i + 1][0]), e5 = EXP2(S[qt2][2 * i + 1][1]); \
        float e6 = EXP2(S[qt2][2 * i + 1][2]), e7 = EXP2(S[qt2][2 * i + 1][3]); \
        union { uint4 u; bf16x8 v; } cv;                                        \
        cv.u.x = pkbf(e0, e1); cv.u.y = pkbf(e2, e3);                           \
        cv.u.z = pkbf(e4, e5); cv.u.w = pkbf(e6, e7);                           \
        pa[qt2][i] = cv.v;                                                      \
      }                                                                         \
    Lacc[0] = MFMA16(pa[0][0], vone, Lacc[0]);                                  \
    Lacc[0] = MFMA16(pa[0][1], vone, Lacc[0]);                                  \
    Lacc[1] = MFMA16(pa[1][0], vone, Lacc[1]);                                  \
    Lacc[1] = MFMA16(pa[1][1], vone, Lacc[1]);                                  \
    bf16x8 Vf[4][2];                                                            \
    _Pragma("unroll") for (int dt = 0; dt < 4; dt++) {                          \
      Vf[dt][0] = *(const bf16x8*)&Vs[off0 + dt * 1024];                        \
      Vf[dt][1] = *(const bf16x8*)&Vs[off1 + dt * 1024];                        \
    }                                                                           \
    _Pragma("unroll") for (int qt2 = 0; qt2 < 2; qt2++)                         \
      _Pragma("unroll") for (int dt = 0; dt < 4; dt++) {                        \
        O[qt2][dt] = MFMA16(pa[qt2][0], Vf[dt][0], O[qt2][dt]);                 \
        O[qt2][dt] = MFMA16(pa[qt2][1], Vf[dt][1], O[qt2][dt]);                 \
      }                                                                         \
    __syncthreads();                                                            \
  }

  for (int kt2 = 0; kt2 < 15; kt2++) {
    ITER(0, 1)
    ITER(1, 1)
  }
  ITER(0, 1)
  ITER(1, 0)
#undef ITER
#undef STAGE

  // epilogue: Lacc[qt2][j] = row-sum for q = qt2*16 + quad*4 + j (all c equal)
  int b_ = bh >> 4, h = bh & 15;
#pragma unroll
  for (int qt2 = 0; qt2 < 2; qt2++) {
    f32x4 linv;
#pragma unroll
    for (int j = 0; j < 4; j++) linv[j] = 1.0f / Lacc[qt2][j];
#pragma unroll
    for (int j = 0; j < 4; j++) {
      int n = qt * 64 + w * 32 + qt2 * 16 + quad * 4 + j;
      u16* op = ot + (((size_t)b_ * 2048 + n) * 16 + h) * 64;
#pragma unroll
      for (int dt = 0; dt < 4; dt++)
        op[dt * 16 + c] = f2bf(O[qt2][dt][j] * linv[j]);
    }
  }
}

// ---------------- output projection GEMM (fp32 out), 64x128 tile ----------
__global__ __launch_bounds__(256) void gemm_out(
    const u16* __restrict__ Aot, const u16* __restrict__ wob,
    const float* __restrict__ bo, float* __restrict__ out)
{
  __shared__ u16 As[64 * 64];
  __shared__ u16 Bs[128 * 64];
  int tid = threadIdx.x, w = tid >> 6, lane = tid & 63;
  int bm = blockIdx.x, bn = blockIdx.y;
  int wm = w >> 1, wn = w & 1;
  f32x4 acc[2][4] = {};
  for (int k0 = 0; k0 < 1024; k0 += 64) {
#pragma unroll
    for (int i = 0; i < 2; i++) {
      int seg = i * 256 + tid;
      int row = seg >> 3, pseg = seg & 7;
      int lseg = pseg ^ (row & 7);
      gld16(Aot + (size_t)(bm * 64 + row) * 1024 + k0 + lseg * 8,
            &As[(i * 256 + tid - (tid & 7)) * 8 + (tid & 7) * 8]);
    }
#pragma unroll
    for (int i = 0; i < 4; i++) {
      int seg = i * 256 + tid;
      int row = seg >> 3, pseg = seg & 7;
      int lseg = pseg ^ (row & 7);
      gld16(wob + (size_t)(bn * 128 + row) * 1024 + k0 + lseg * 8,
            &Bs[(i * 256 + tid - (tid & 7)) * 8 + (tid & 7) * 8]);
    }
    __syncthreads();
#pragma unroll
    for (int ks = 0; ks < 2; ks++) {
      bf16x8 af[2], bfr[4];
#pragma unroll
      for (int mt = 0; mt < 2; mt++) {
        int row = wm * 32 + mt * 16 + (lane & 15);
        int cseg = (ks * 4 + (lane >> 4)) ^ (row & 7);
        af[mt] = *(const bf16x8*)&As[(row * 8 + cseg) * 8];
      }
#pragma unroll
      for (int nt = 0; nt < 4; nt++) {
        int row = wn * 64 + nt * 16 + (lane & 15);
        int cseg = (ks * 4 + (lane >> 4)) ^ (row & 7);
        bfr[nt] = *(const bf16x8*)&Bs[(row * 8 + cseg) * 8];
      }
#pragma unroll
      for (int mt = 0; mt < 2; mt++)
#pragma unroll
        for (int nt = 0; nt < 4; nt++)
          acc[mt][nt] = MFMA16(af[mt], bfr[nt], acc[mt][nt]);
    }
    __syncthreads();
  }
#pragma unroll
  for (int nt = 0; nt < 4; nt++) {
    int o = bn * 128 + wn * 64 + nt * 16 + (lane & 15);
    float bval = bo[o];
#pragma unroll
    for (int mt = 0; mt < 2; mt++)
#pragma unroll
      for (int j = 0; j < 4; j++) {
        int m = bm * 64 + wm * 32 + mt * 16 + (lane >> 4) * 4 + j;
        out[(size_t)m * 1024 + o] = acc[mt][nt][j] + bval;
      }
  }
}

extern "C" void kernel_launch(void* const* d_in, const int* in_sizes, int n_in,
                              void* d_out, int out_size, void* d_ws, size_t ws_size,
                              hipStream_t stream)
{
  const float* x  = (const float*)d_in[0];
  const float* qu = (const float*)d_in[1];
  const float* wq = (const float*)d_in[2];
  const float* bq = (const float*)d_in[3];
  const float* wk = (const float*)d_in[4];
  const float* bk = (const float*)d_in[5];
  const float* wv = (const float*)d_in[6];
  const float* bv = (const float*)d_in[7];
  const float* wo = (const float*)d_in[8];
  const float* bo = (const float*)d_in[9];
  float* out = (float*)d_out;
  char* ws = (char*)d_ws;
  u16* xb  = (u16*)(ws + (size_t)0);          // 8 MB
  u16* qub = (u16*)(ws + ((size_t)8  << 20)); // 8 MB
  u16* wqb = (u16*)(ws + ((size_t)16 << 20)); // 2 MB
  u16* wkb = (u16*)(ws + ((size_t)18 << 20)); // 2 MB
  u16* wvb = (u16*)(ws + ((size_t)20 << 20)); // 2 MB
  u16* wob = (u16*)(ws + ((size_t)22 << 20)); // 2 MB
  u16* qhd = (u16*)(ws + ((size_t)24 << 20)); // 8 MB  Q-scaled [B,H,N,D]
  u16* khd = (u16*)(ws + ((size_t)32 << 20)); // 8 MB  K [B,H,N,D]
  u16* vtd = (u16*)(ws + ((size_t)40 << 20)); // 8 MB  V^T permuted [B,H,D,N']
  u16* otd = (u16*)(ws + ((size_t)48 << 20)); // 8 MB  attn out [B,N,H,D]

  cast_all<<<12288, 256, 0, stream>>>(x, qu, wq, wk, wv, wo,
                                      xb, qub, wqb, wkb, wvb, wob);
  gemm_qkv<<<dim3(32, 8, 3), 256, 0, stream>>>(qub, xb, wqb, wkb, wvb,
                                               bq, bk, bv, qhd, khd, vtd);
  attn<<<dim3(32, 32), 128, 0, stream>>>(qhd, khd, vtd, otd);
  gemm_out<<<dim3(64, 8), 256, 0, stream>>>(otd, wob, bo, out);
}